// Round 7
// baseline (887.968 us; speedup 1.0000x reference)
//
#include <hip/hip_runtime.h>
#include <hip/hip_fp16.h>
#include <math.h>

#define BLK 256

// ---------------------------------------------------------------------------
// GCNPolicyNetwork: 3-layer improved-GCN + masked softmax + mean-pool value.
// Round 7: EDGE-CENTRIC rewrite. R5/R6 showed per-node gather chains are
// latency-bound (~50us/layer vs ~10us traffic floor); lane-mapping tweaks
// didn't move it. Now each agg block owns a 256-node bucket with an fp32
// accumulator tile in LDS (acc[256][17], pad kills bank conflicts); edges
// stream COALESCED from packed[] ((row<<8)|col_local, bucket-sorted by k_bin);
// a 4-lane team per edge does one 32B fp16 gather + 4 LDS float atomics.
// No serial chains -> loads pipeline deeply. k_place/srcs are DELETED
// (agg consumes packed[] directly); k_deg computes dinv per bucket.
// ---------------------------------------------------------------------------

#define BSH 8                    // 256 nodes per bucket
#define NB 512                   // bucket-array size (nbuck=391 <= 512)
#define EB 8192                  // edges per binning block
#define BINTH 512                // k_bin block size
#define AGT 512                  // agg block size (128 teams of 4 lanes)

// ---- fp16 payload helpers (4 features per lane = 8 B) ----
__device__ inline float4 load_h4(const __half* base, int node, int sub) {
    const uint2* p = reinterpret_cast<const uint2*>(base + ((size_t)node << 4)) + sub;
    uint2 u = *p;
    union { unsigned u; __half2 h; } a, b;
    a.u = u.x; b.u = u.y;
    float2 fa = __half22float2(a.h), fb = __half22float2(b.h);
    return make_float4(fa.x, fa.y, fb.x, fb.y);
}

__device__ inline void store_h4(__half* base, int node, int sub, float4 v) {
    union { unsigned u; __half2 h; } a, b;
    a.h = __floats2half2_rn(v.x, v.y);
    b.h = __floats2half2_rn(v.z, v.w);
    uint2 u; u.x = a.u; u.y = b.u;
    *(reinterpret_cast<uint2*>(base + ((size_t)node << 4)) + sub) = u;
}

// per-block LDS histogram of bucket ids, flush with <=391 global atomics
__global__ void __launch_bounds__(BLK) k_bcount(const int* __restrict__ col,
                                                int* __restrict__ bcnt, int E) {
    __shared__ int hist[NB];
    int tid = threadIdx.x;
    int base = blockIdx.x * EB;
    int cnt = min(EB, E - base);
    hist[tid] = 0; hist[tid + 256] = 0;
    __syncthreads();
    for (int j = tid; j < cnt; j += BLK)
        atomicAdd(&hist[col[base + j] >> BSH], 1);
    __syncthreads();
    if (hist[tid] > 0) atomicAdd(&bcnt[tid], hist[tid]);
    if (hist[tid + 256] > 0) atomicAdd(&bcnt[tid + 256], hist[tid + 256]);
}

// single-block exclusive scan of bucket counts -> gcur (mutable) + bbase (kept)
__global__ void __launch_bounds__(NB) k_bscan(const int* __restrict__ bcnt,
                                              int* __restrict__ gcur,
                                              int* __restrict__ bbase, int nbuck) {
    __shared__ int s[NB];
    int tid = threadIdx.x;
    int v = (tid < nbuck) ? bcnt[tid] : 0;
    s[tid] = v;
    __syncthreads();
    for (int d = 1; d < NB; d <<= 1) {
        int t = (tid >= d) ? s[tid - d] : 0;
        __syncthreads();
        if (tid >= d) s[tid] += t;
        __syncthreads();
    }
    int ex = s[tid] - v;
    gcur[tid] = ex;
    bbase[tid] = ex;
}

// pass 1: LDS multisplit of edges into 256-node buckets, coalesced flush
__global__ void __launch_bounds__(BINTH) k_bin(const int* __restrict__ row,
                                               const int* __restrict__ col,
                                               int* __restrict__ gcur,
                                               int* __restrict__ packed, int E) {
    __shared__ int stage[EB];            // packed edges, bucket-sorted locally
    __shared__ unsigned short sbuk[EB];  // bucket id per staged slot
    __shared__ int hist[NB];
    __shared__ int lscan[NB];
    __shared__ int cur[NB];
    __shared__ int gbase[NB];
    int tid = threadIdx.x;
    int base = blockIdx.x * EB;
    int cnt = min(EB, E - base);

    hist[tid] = 0;
    __syncthreads();
    for (int j = tid; j < cnt; j += BINTH) {
        int c = col[base + j];
        atomicAdd(&hist[c >> BSH], 1);
    }
    __syncthreads();
    lscan[tid] = hist[tid];
    __syncthreads();
    for (int d = 1; d < NB; d <<= 1) {
        int t = (tid >= d) ? lscan[tid - d] : 0;
        __syncthreads();
        if (tid >= d) lscan[tid] += t;
        __syncthreads();
    }
    {
        int ex = lscan[tid] - hist[tid];
        lscan[tid] = ex;
        cur[tid] = ex;
    }
    __syncthreads();
    for (int j = tid; j < cnt; j += BINTH) {
        int c = col[base + j];
        int r = row[base + j];
        int b = c >> BSH;
        int p = atomicAdd(&cur[b], 1);
        stage[p] = (r << BSH) | (c & ((1 << BSH) - 1));
        sbuk[p] = (unsigned short)b;
    }
    __syncthreads();
    if (hist[tid] > 0) gbase[tid] = atomicAdd(&gcur[tid], hist[tid]);
    __syncthreads();
    for (int j = tid; j < cnt; j += BINTH) {
        int b = sbuk[j];
        int pos = gbase[b] + (j - lscan[b]);
        packed[pos] = stage[j];
    }
}

// per-bucket degree histogram -> dinv only (no CSR placement needed anymore)
__global__ void __launch_bounds__(BLK) k_deg(const int* __restrict__ packed,
                                             const int* __restrict__ bbase,
                                             const int* __restrict__ bcnt,
                                             float* __restrict__ dinv, int n) {
    __shared__ int hist[1 << BSH];
    int tid = threadIdx.x;
    int b = blockIdx.x;
    hist[tid] = 0;
    __syncthreads();
    int ebeg = bbase[b], ecnt = bcnt[b];
    for (int j = tid; j < ecnt; j += BLK)
        atomicAdd(&hist[packed[ebeg + j] & 255], 1);
    __syncthreads();
    int i = (b << BSH) + tid;
    if (i < n) dinv[i] = rsqrtf((float)hist[tid] + 2.0f);
}

// layer-1 transform: hwsA = dinv * (x @ W1)   (x is N x 3), fp16 store
__global__ void __launch_bounds__(BLK) k_l1(const float* __restrict__ x,
                                            const float* __restrict__ W1,
                                            const float* __restrict__ dinv,
                                            __half* __restrict__ hwsA, int n) {
    __shared__ float w[48];
    if (threadIdx.x < 48) w[threadIdx.x] = W1[threadIdx.x];
    __syncthreads();
    int i = blockIdx.x * BLK + threadIdx.x;
    if (i >= n) return;
    float x0 = x[i * 3 + 0], x1 = x[i * 3 + 1], x2 = x[i * 3 + 2];
    float di = dinv[i];
#pragma unroll
    for (int sub = 0; sub < 4; sub++) {
        float4 o;
        float* op = &o.x;
#pragma unroll
        for (int k = 0; k < 4; k++) {
            int f = sub * 4 + k;
            op[k] = di * (x0 * w[f] + x1 * w[16 + f] + x2 * w[32 + f]);
        }
        store_h4(hwsA, i, sub, o);
    }
}

// accumulate one gathered float4 into the LDS tile for local node li
#define ACC4(LI, Q)                                                             \
    {                                                                           \
        float* a = &acc[(LI) * 17 + sub * 4];                                   \
        atomicAdd(a + 0, (Q).x); atomicAdd(a + 1, (Q).y);                       \
        atomicAdd(a + 2, (Q).z); atomicAdd(a + 3, (Q).w);                       \
    }

// edge-streaming phase shared by agg1/agg2: team of 4 lanes per edge, x4 unroll
#define EDGE_STREAM(HWS)                                                        \
    {                                                                           \
        int team = tid >> 2;                                                    \
        int e = team;                                                           \
        for (; e + 384 < ecnt; e += 512) {                                      \
            int v0 = packed[ebeg + e];                                          \
            int v1 = packed[ebeg + e + 128];                                    \
            int v2 = packed[ebeg + e + 256];                                    \
            int v3 = packed[ebeg + e + 384];                                    \
            float4 q0 = load_h4(HWS, v0 >> BSH, sub);                           \
            float4 q1 = load_h4(HWS, v1 >> BSH, sub);                           \
            float4 q2 = load_h4(HWS, v2 >> BSH, sub);                           \
            float4 q3 = load_h4(HWS, v3 >> BSH, sub);                           \
            ACC4(v0 & 255, q0); ACC4(v1 & 255, q1);                             \
            ACC4(v2 & 255, q2); ACC4(v3 & 255, q3);                             \
        }                                                                       \
        for (; e < ecnt; e += 128) {                                            \
            int v0 = packed[ebeg + e];                                          \
            float4 q0 = load_h4(HWS, v0 >> BSH, sub);                           \
            ACC4(v0 & 255, q0);                                                 \
        }                                                                       \
    }

// layer-1 aggregate + relu + layer-2 transform: hwsB = dinv * (h1 @ W2)
__global__ void __launch_bounds__(AGT) k_agg1(const __half* __restrict__ hwsA,
                                              const int* __restrict__ packed,
                                              const int* __restrict__ bbase,
                                              const int* __restrict__ bcnt,
                                              const float* __restrict__ dinv,
                                              const float* __restrict__ b1,
                                              const float* __restrict__ W2,
                                              __half* __restrict__ hwsB, int n) {
    __shared__ float acc[256 * 17];
    __shared__ float w[256];
    __shared__ float bb[16];
    int tid = threadIdx.x;
    int sub = tid & 3;
    for (int t = tid; t < 256 * 17; t += AGT) acc[t] = 0.f;
    if (tid < 256) w[tid] = W2[tid];
    if (tid < 16) bb[tid] = b1[tid];
    __syncthreads();
    int b = blockIdx.x;
    int ebeg = bbase[b], ecnt = bcnt[b];
    EDGE_STREAM(hwsA);
    __syncthreads();
    int i = (b << BSH) + tid;
    if (tid < 256 && i < n) {
        float di = dinv[i];
        float h[16];
#pragma unroll
        for (int s = 0; s < 4; s++) {
            float4 sf = load_h4(hwsA, i, s);
            h[s * 4 + 0] = fmaxf(di * (acc[tid * 17 + s * 4 + 0] + 2.f * sf.x) + bb[s * 4 + 0], 0.f);
            h[s * 4 + 1] = fmaxf(di * (acc[tid * 17 + s * 4 + 1] + 2.f * sf.y) + bb[s * 4 + 1], 0.f);
            h[s * 4 + 2] = fmaxf(di * (acc[tid * 17 + s * 4 + 2] + 2.f * sf.z) + bb[s * 4 + 2], 0.f);
            h[s * 4 + 3] = fmaxf(di * (acc[tid * 17 + s * 4 + 3] + 2.f * sf.w) + bb[s * 4 + 3], 0.f);
        }
#pragma unroll
        for (int s = 0; s < 4; s++) {
            float o0 = 0.f, o1 = 0.f, o2 = 0.f, o3 = 0.f;
#pragma unroll
            for (int f = 0; f < 16; f++) {
                float hv = h[f];
                const float4 wq = *(const float4*)&w[f * 16 + s * 4];
                o0 += hv * wq.x; o1 += hv * wq.y; o2 += hv * wq.z; o3 += hv * wq.w;
            }
            store_h4(hwsB, i, s, make_float4(di * o0, di * o1, di * o2, di * o3));
        }
    }
}

// layer-2 aggregate + relu (-> h2), pool accumulation, layer-3 transform
__global__ void __launch_bounds__(AGT) k_agg2(const __half* __restrict__ hwsB,
                                              const int* __restrict__ packed,
                                              const int* __restrict__ bbase,
                                              const int* __restrict__ bcnt,
                                              const float* __restrict__ dinv,
                                              const float* __restrict__ b2,
                                              const float* __restrict__ W3,
                                              float* __restrict__ hws3,
                                              float* __restrict__ pool, int n) {
    __shared__ float acc[256 * 17];
    __shared__ float w3[16];
    __shared__ float bb[16];
    __shared__ float lp[16];
    int tid = threadIdx.x;
    int sub = tid & 3;
    for (int t = tid; t < 256 * 17; t += AGT) acc[t] = 0.f;
    if (tid < 16) { w3[tid] = W3[tid]; bb[tid] = b2[tid]; lp[tid] = 0.f; }
    __syncthreads();
    int b = blockIdx.x;
    int ebeg = bbase[b], ecnt = bcnt[b];
    EDGE_STREAM(hwsB);
    __syncthreads();
    int i = (b << BSH) + tid;
    if (tid < 256 && i < n) {
        float di = dinv[i];
        float h[16];
#pragma unroll
        for (int s = 0; s < 4; s++) {
            float4 sf = load_h4(hwsB, i, s);
            h[s * 4 + 0] = fmaxf(di * (acc[tid * 17 + s * 4 + 0] + 2.f * sf.x) + bb[s * 4 + 0], 0.f);
            h[s * 4 + 1] = fmaxf(di * (acc[tid * 17 + s * 4 + 1] + 2.f * sf.y) + bb[s * 4 + 1], 0.f);
            h[s * 4 + 2] = fmaxf(di * (acc[tid * 17 + s * 4 + 2] + 2.f * sf.z) + bb[s * 4 + 2], 0.f);
            h[s * 4 + 3] = fmaxf(di * (acc[tid * 17 + s * 4 + 3] + 2.f * sf.w) + bb[s * 4 + 3], 0.f);
        }
        float hw3 = 0.f;
#pragma unroll
        for (int f = 0; f < 16; f++) hw3 += h[f] * w3[f];
        hws3[i] = di * hw3;
#pragma unroll
        for (int f = 0; f < 16; f++) atomicAdd(&lp[f], h[f]);
    }
    __syncthreads();
    if (tid < 16) atomicAdd(&pool[tid], lp[tid]);
}

// layer-3 aggregate (scalar) -> logits c[n]; per-block max of masked logits
__global__ void __launch_bounds__(AGT) k_agg3(const float* __restrict__ hws3,
                                              const int* __restrict__ packed,
                                              const int* __restrict__ bbase,
                                              const int* __restrict__ bcnt,
                                              const float* __restrict__ dinv,
                                              const float* __restrict__ b3,
                                              const int* __restrict__ choices,
                                              float* __restrict__ cbuf,
                                              float* __restrict__ pmax, int n) {
    __shared__ float acc1[256];
    __shared__ float red[AGT];
    int tid = threadIdx.x;
    if (tid < 256) acc1[tid] = 0.f;
    __syncthreads();
    int b = blockIdx.x;
    int ebeg = bbase[b], ecnt = bcnt[b];
    int e = tid;
    for (; e + 3 * AGT < ecnt; e += 4 * AGT) {
        int v0 = packed[ebeg + e];
        int v1 = packed[ebeg + e + AGT];
        int v2 = packed[ebeg + e + 2 * AGT];
        int v3 = packed[ebeg + e + 3 * AGT];
        float q0 = hws3[v0 >> BSH];
        float q1 = hws3[v1 >> BSH];
        float q2 = hws3[v2 >> BSH];
        float q3 = hws3[v3 >> BSH];
        atomicAdd(&acc1[v0 & 255], q0);
        atomicAdd(&acc1[v1 & 255], q1);
        atomicAdd(&acc1[v2 & 255], q2);
        atomicAdd(&acc1[v3 & 255], q3);
    }
    for (; e < ecnt; e += AGT) {
        int v0 = packed[ebeg + e];
        float q0 = hws3[v0 >> BSH];
        atomicAdd(&acc1[v0 & 255], q0);
    }
    __syncthreads();
    float logit = -INFINITY;
    int i = (b << BSH) + tid;
    if (tid < 256 && i < n) {
        float c = dinv[i] * (acc1[tid] + 2.f * hws3[i]) + b3[0];
        cbuf[i] = c;
        if (choices[i] != 0) logit = c;
    }
    red[tid] = logit;
    __syncthreads();
    for (int d = AGT / 2; d > 0; d >>= 1) {
        if (tid < d) red[tid] = fmaxf(red[tid], red[tid + d]);
        __syncthreads();
    }
    if (tid == 0) pmax[blockIdx.x] = red[0];
}

__global__ void k_redmax(const float* __restrict__ pmax, float* __restrict__ scal_m, int nblk) {
    __shared__ float red[BLK];
    float m = -INFINITY;
    for (int i = threadIdx.x; i < nblk; i += BLK) m = fmaxf(m, pmax[i]);
    red[threadIdx.x] = m;
    __syncthreads();
    for (int d = BLK / 2; d > 0; d >>= 1) {
        if (threadIdx.x < d) red[threadIdx.x] = fmaxf(red[threadIdx.x], red[threadIdx.x + d]);
        __syncthreads();
    }
    if (threadIdx.x == 0) scal_m[0] = red[0];
}

__global__ void __launch_bounds__(BLK) k_sumexp(const float* __restrict__ cbuf,
                                                const int* __restrict__ choices,
                                                const float* __restrict__ scal_m,
                                                float* __restrict__ Ssum, int n) {
    __shared__ float red[BLK];
    int i = blockIdx.x * BLK + threadIdx.x;
    float m = scal_m[0];
    float v = 0.0f;
    if (i < n && choices[i] != 0) v = expf(cbuf[i] - m);
    red[threadIdx.x] = v;
    __syncthreads();
    for (int d = BLK / 2; d > 0; d >>= 1) {
        if (threadIdx.x < d) red[threadIdx.x] += red[threadIdx.x + d];
        __syncthreads();
    }
    if (threadIdx.x == 0) atomicAdd(Ssum, red[0]);
}

__global__ void __launch_bounds__(BLK) k_final(const float* __restrict__ cbuf,
                                               const int* __restrict__ choices,
                                               const float* __restrict__ scal_m,
                                               const float* __restrict__ Ssum,
                                               const float* __restrict__ pool,
                                               const float* __restrict__ fcw,
                                               const float* __restrict__ fcb,
                                               float* __restrict__ out, int n) {
    int i = blockIdx.x * BLK + threadIdx.x;
    if (i < n) {
        float p = 0.0f;
        if (choices[i] != 0) {
            float m = scal_m[0], S = Ssum[0];
            p = expf(cbuf[i] - m) / S;
        }
        out[i] = p;
    }
    if (blockIdx.x == 0 && threadIdx.x == 0) {
        float invn = 1.0f / (float)n;
        float v = 0.0f;
#pragma unroll
        for (int f = 0; f < 16; f++) v += (pool[f] * invn) * fcw[f];
        out[n] = v + fcb[0];
    }
}

extern "C" void kernel_launch(void* const* d_in, const int* in_sizes, int n_in,
                              void* d_out, int out_size, void* d_ws, size_t ws_size,
                              hipStream_t stream) {
    const float* x       = (const float*)d_in[0];
    const int*   ei      = (const int*)d_in[1];
    const int*   choices = (const int*)d_in[2];
    const float* W1 = (const float*)d_in[3];
    const float* b1 = (const float*)d_in[4];
    const float* W2 = (const float*)d_in[5];
    const float* b2 = (const float*)d_in[6];
    const float* W3 = (const float*)d_in[7];
    const float* b3 = (const float*)d_in[8];
    const float* fcw = (const float*)d_in[9];
    const float* fcb = (const float*)d_in[10];
    float* out = (float*)d_out;

    int n = in_sizes[0] / 3;
    int E = in_sizes[1] / 2;
    const int* row = ei;
    const int* col = ei + E;

    int nblkN = (n + BLK - 1) / BLK;           // 391
    int nbuck = (n + (1 << BSH) - 1) >> BSH;   // 391 buckets of 256 nodes
    int nblkBin = (E + EB - 1) / EB;           // 391 binning blocks

    // workspace layout (16B aligned slices)
    char* ws = (char*)d_ws;
    size_t o = 0;
    auto alloc = [&](size_t bytes) { char* p = ws + o; o += (bytes + 15) & ~(size_t)15; return p; };
    float* dinv   = (float*)alloc((size_t)n * 4);
    float* hws3   = (float*)alloc((size_t)n * 4);
    float* cbuf   = (float*)alloc((size_t)n * 4);
    float* pmax   = (float*)alloc(4096);       // >= nbuck floats
    int*   bcnt   = (int*)  alloc(NB * 4);
    int*   gcur   = (int*)  alloc(NB * 4);
    int*   bbase  = (int*)  alloc(NB * 4);
    float* scal   = (float*)alloc(256);   // [0]=S, [1..16]=pool, [17]=m
    float* Ssum   = scal + 0;
    float* pool   = scal + 1;
    float* scal_m = scal + 17;
    int*    packed = (int*)  alloc((size_t)E * 4);       // lives whole pipeline now
    __half* hwsA   = (__half*)alloc((size_t)n * 16 * 2);
    __half* hwsB   = (__half*)alloc((size_t)n * 16 * 2);
    (void)ws_size;  // ~20 MB used

    hipMemsetAsync(bcnt, 0, NB * 4, stream);
    hipMemsetAsync(scal, 0, 68, stream);   // S + pool[16]

    // ---- bucket build (no srcs placement pass anymore) ----
    k_bcount<<<nblkBin, BLK, 0, stream>>>(col, bcnt, E);
    k_bscan<<<1, NB, 0, stream>>>(bcnt, gcur, bbase, nbuck);
    k_bin<<<nblkBin, BINTH, 0, stream>>>(row, col, gcur, packed, E);
    k_deg<<<nbuck, BLK, 0, stream>>>(packed, bbase, bcnt, dinv, n);

    // ---- GCN layers (edge-centric, bucket-LDS accumulation) ----
    k_l1<<<nblkN, BLK, 0, stream>>>(x, W1, dinv, hwsA, n);
    k_agg1<<<nbuck, AGT, 0, stream>>>(hwsA, packed, bbase, bcnt, dinv, b1, W2, hwsB, n);
    k_agg2<<<nbuck, AGT, 0, stream>>>(hwsB, packed, bbase, bcnt, dinv, b2, W3, hws3, pool, n);
    k_agg3<<<nbuck, AGT, 0, stream>>>(hws3, packed, bbase, bcnt, dinv, b3, choices, cbuf, pmax, n);

    // ---- softmax + value head ----
    k_redmax<<<1, BLK, 0, stream>>>(pmax, scal_m, nbuck);
    k_sumexp<<<nblkN, BLK, 0, stream>>>(cbuf, choices, scal_m, Ssum, n);
    k_final<<<nblkN, BLK, 0, stream>>>(cbuf, choices, scal_m, Ssum, pool, fcw, fcb, out, n);
}

// Round 8
// 260.985 us; speedup vs baseline: 3.4024x; 3.4024x over previous
//
#include <hip/hip_runtime.h>
#include <hip/hip_fp16.h>
#include <math.h>

#define BLK 256

// ---------------------------------------------------------------------------
// GCNPolicyNetwork: 3-layer improved-GCN + masked softmax + mean-pool value.
// Round 8: reverted to R5's node-centric 4-lane gather (R6 lane remap and R7
// edge-centric LDS-atomics both regressed; R7 by 3x - LDS atomic serialization).
// New: (1) RANK-3 trick for layer 1: agg commutes with x@W1, so gather only
// xs = dinv*x (half4, 8 B/edge, 0.8 MB working set) and apply W1 after
// aggregation; k_l1 deleted (xs built in k_place epilogue). (2) BSH 9->8:
// k_place gets 391 blocks (was 196, half-idle GPU). (3) NT loads on k_bin's
// row/col. k_agg2/k_agg3 unchanged from R5 as an A/B control.
// ---------------------------------------------------------------------------

#define BSH 8                    // 256 nodes per bucket
#define NB 512                   // bucket-array size (nbuck=391 <= 512)
#define EB 8192                  // edges per binning block
#define BINTH 512                // k_bin block size

// ---- fp16 payload helpers ----
__device__ inline float4 load_h4(const __half* base, int node, int sub) {
    const uint2* p = reinterpret_cast<const uint2*>(base + ((size_t)node << 4)) + sub;
    uint2 u = *p;
    union { unsigned u; __half2 h; } a, b;
    a.u = u.x; b.u = u.y;
    float2 fa = __half22float2(a.h), fb = __half22float2(b.h);
    return make_float4(fa.x, fa.y, fb.x, fb.y);
}

__device__ inline void store_h4(__half* base, int node, int sub, float4 v) {
    union { unsigned u; __half2 h; } a, b;
    a.h = __floats2half2_rn(v.x, v.y);
    b.h = __floats2half2_rn(v.z, v.w);
    uint2 u; u.x = a.u; u.y = b.u;
    *(reinterpret_cast<uint2*>(base + ((size_t)node << 4)) + sub) = u;
}

// xs payload: half4 (dinv*x0, dinv*x1, dinv*x2, 0) = 8 B per node
__device__ inline float3 load_xs(const __half* xs, int node) {
    uint2 u = *reinterpret_cast<const uint2*>(xs + ((size_t)node << 2));
    union { unsigned u; __half2 h; } a, b;
    a.u = u.x; b.u = u.y;
    float2 fa = __half22float2(a.h), fb = __half22float2(b.h);
    return make_float3(fa.x, fa.y, fb.x);
}

// per-block LDS histogram of bucket ids, flush with few global atomics
__global__ void __launch_bounds__(BLK) k_bcount(const int* __restrict__ col,
                                                int* __restrict__ bcnt, int E) {
    __shared__ int hist[NB];
    int tid = threadIdx.x;
    int base = blockIdx.x * EB;
    int cnt = min(EB, E - base);
    hist[tid] = 0; hist[tid + 256] = 0;
    __syncthreads();
    for (int j = tid; j < cnt; j += BLK)
        atomicAdd(&hist[col[base + j] >> BSH], 1);
    __syncthreads();
    if (hist[tid] > 0) atomicAdd(&bcnt[tid], hist[tid]);
    if (hist[tid + 256] > 0) atomicAdd(&bcnt[tid + 256], hist[tid + 256]);
}

// single-block exclusive scan of bucket counts -> gcur (mutable) + bbase (kept)
__global__ void __launch_bounds__(NB) k_bscan(const int* __restrict__ bcnt,
                                              int* __restrict__ gcur,
                                              int* __restrict__ bbase, int nbuck) {
    __shared__ int s[NB];
    int tid = threadIdx.x;
    int v = (tid < nbuck) ? bcnt[tid] : 0;
    s[tid] = v;
    __syncthreads();
    for (int d = 1; d < NB; d <<= 1) {
        int t = (tid >= d) ? s[tid - d] : 0;
        __syncthreads();
        if (tid >= d) s[tid] += t;
        __syncthreads();
    }
    int ex = s[tid] - v;
    gcur[tid] = ex;
    bbase[tid] = ex;
}

// pass 1: LDS multisplit of edges into 256-node buckets, coalesced flush
__global__ void __launch_bounds__(BINTH) k_bin(const int* __restrict__ row,
                                               const int* __restrict__ col,
                                               int* __restrict__ gcur,
                                               int* __restrict__ packed, int E) {
    __shared__ int stage[EB];
    __shared__ unsigned short sbuk[EB];
    __shared__ int hist[NB];
    __shared__ int lscan[NB];
    __shared__ int cur[NB];
    __shared__ int gbase[NB];
    int tid = threadIdx.x;
    int base = blockIdx.x * EB;
    int cnt = min(EB, E - base);

    hist[tid] = 0;
    __syncthreads();
    for (int j = tid; j < cnt; j += BINTH) {
        int c = __builtin_nontemporal_load(col + base + j);
        atomicAdd(&hist[c >> BSH], 1);
    }
    __syncthreads();
    lscan[tid] = hist[tid];
    __syncthreads();
    for (int d = 1; d < NB; d <<= 1) {
        int t = (tid >= d) ? lscan[tid - d] : 0;
        __syncthreads();
        if (tid >= d) lscan[tid] += t;
        __syncthreads();
    }
    {
        int ex = lscan[tid] - hist[tid];
        lscan[tid] = ex;
        cur[tid] = ex;
    }
    __syncthreads();
    for (int j = tid; j < cnt; j += BINTH) {
        int c = __builtin_nontemporal_load(col + base + j);
        int r = __builtin_nontemporal_load(row + base + j);
        int b = c >> BSH;
        int p = atomicAdd(&cur[b], 1);
        stage[p] = (r << BSH) | (c & ((1 << BSH) - 1));
        sbuk[p] = (unsigned short)b;
    }
    __syncthreads();
    if (hist[tid] > 0) gbase[tid] = atomicAdd(&gcur[tid], hist[tid]);
    __syncthreads();
    for (int j = tid; j < cnt; j += BINTH) {
        int b = sbuk[j];
        int pos = gbase[b] + (j - lscan[b]);
        packed[pos] = stage[j];
    }
}

// pass 2: per-bucket degree count + scan -> degi/offs/dinv/xs + fine placement
__global__ void __launch_bounds__(BLK) k_place(const int* __restrict__ packed,
                                               const int* __restrict__ bbase,
                                               const int* __restrict__ bcnt,
                                               const float* __restrict__ x,
                                               int* __restrict__ degi,
                                               int* __restrict__ offs,
                                               float* __restrict__ dinv,
                                               __half* __restrict__ xs,
                                               int* __restrict__ srcs, int n) {
    __shared__ int cnt[256];
    __shared__ int lcur[256];
    __shared__ int ssum[256];
    int tid = threadIdx.x;
    int b = blockIdx.x;
    int nb0 = b << BSH;
    cnt[tid] = 0;
    __syncthreads();
    int pbeg = bbase[b];
    int ecnt = bcnt[b];
    for (int j = tid; j < ecnt; j += BLK)
        atomicAdd(&cnt[packed[pbeg + j] & 255], 1);
    __syncthreads();
    int c = cnt[tid];
    ssum[tid] = c;
    __syncthreads();
    for (int d = 1; d < 256; d <<= 1) {
        int t = (tid >= d) ? ssum[tid - d] : 0;
        __syncthreads();
        if (tid >= d) ssum[tid] += t;
        __syncthreads();
    }
    int ex = ssum[tid] - c;
    lcur[tid] = ex;
    int i = nb0 + tid;
    if (i < n) {
        degi[i] = c;
        offs[i] = pbeg + ex;
        float di = rsqrtf((float)c + 2.0f);
        dinv[i] = di;
        float x0 = x[i * 3 + 0], x1 = x[i * 3 + 1], x2 = x[i * 3 + 2];
        union { unsigned u; __half2 h; } a2, b2;
        a2.h = __floats2half2_rn(di * x0, di * x1);
        b2.h = __floats2half2_rn(di * x2, 0.f);
        uint2 u; u.x = a2.u; u.y = b2.u;
        *reinterpret_cast<uint2*>(xs + ((size_t)i << 2)) = u;
    }
    __syncthreads();
    for (int j = tid; j < ecnt; j += BLK) {
        int v = packed[pbeg + j];
        int li = v & 255;
        int r = v >> BSH;
        int slot = atomicAdd(&lcur[li], 1);
        srcs[pbeg + slot] = r;
    }
}

// layer-1: rank-3 aggregation of xs, then @W1 + relu, then @W2 -> hwsB (fp16).
// 4 lanes/node; lane sub walks j=beg+sub stride 4 (one 8B load per edge).
__global__ void __launch_bounds__(BLK) k_agg1(const __half* __restrict__ xs,
                                              const int* __restrict__ offs,
                                              const int* __restrict__ degi,
                                              const int* __restrict__ srcs,
                                              const float* __restrict__ dinv,
                                              const float* __restrict__ b1,
                                              const float* __restrict__ W1,
                                              const float* __restrict__ W2,
                                              __half* __restrict__ hwsB, int n) {
    __shared__ float w1[48];
    __shared__ float w2[256];
    __shared__ float bb[16];
    __shared__ float hbuf[64][17];
    int tid = threadIdx.x;
    w2[tid] = W2[tid];
    if (tid < 48) w1[tid] = W1[tid];
    if (tid < 16) bb[tid] = b1[tid];
    __syncthreads();
    int nl = tid >> 2, sub = tid & 3;
    int i = blockIdx.x * 64 + nl;
    bool act = (i < n);
    float di = 0.f;
    if (act) {
        di = dinv[i];
        float ax = 0.f, ay = 0.f, az = 0.f;
        float bx = 0.f, by = 0.f, bz = 0.f;
        int beg = offs[i], end = beg + degi[i];
        int j = beg + sub;
        for (; j + 12 < end; j += 16) {
            int r0 = srcs[j], r1 = srcs[j + 4], r2 = srcs[j + 8], r3 = srcs[j + 12];
            float3 q0 = load_xs(xs, r0);
            float3 q1 = load_xs(xs, r1);
            float3 q2 = load_xs(xs, r2);
            float3 q3 = load_xs(xs, r3);
            ax += q0.x; ay += q0.y; az += q0.z;
            bx += q1.x; by += q1.y; bz += q1.z;
            ax += q2.x; ay += q2.y; az += q2.z;
            bx += q3.x; by += q3.y; bz += q3.z;
        }
        for (; j < end; j += 4) {
            float3 q0 = load_xs(xs, srcs[j]);
            ax += q0.x; ay += q0.y; az += q0.z;
        }
        ax += bx; ay += by; az += bz;
        // combine across the node's 4 lanes
        ax += __shfl_xor(ax, 1); ay += __shfl_xor(ay, 1); az += __shfl_xor(az, 1);
        ax += __shfl_xor(ax, 2); ay += __shfl_xor(ay, 2); az += __shfl_xor(az, 2);
        // self-loop term
        float3 s = load_xs(xs, i);
        ax += 2.f * s.x; ay += 2.f * s.y; az += 2.f * s.z;
        // h1 features for this lane's slice: relu(di*(agg @ W1) + b1)
#pragma unroll
        for (int k = 0; k < 4; k++) {
            int f = sub * 4 + k;
            float hv = di * (ax * w1[f] + ay * w1[16 + f] + az * w1[32 + f]) + bb[f];
            hbuf[nl][f] = fmaxf(hv, 0.f);
        }
    }
    __syncthreads();
    if (act) {
        const float* hn = hbuf[nl];
        float s0 = 0.f, s1 = 0.f, s2 = 0.f, s3 = 0.f;
#pragma unroll
        for (int f = 0; f < 16; f++) {
            float hv = hn[f];
            const float4 wq = *(const float4*)&w2[f * 16 + sub * 4];
            s0 += hv * wq.x; s1 += hv * wq.y; s2 += hv * wq.z; s3 += hv * wq.w;
        }
        store_h4(hwsB, i, sub, make_float4(di * s0, di * s1, di * s2, di * s3));
    }
}

// R5 gather: 4 lanes/node, fp16 payload, x4 unroll (CONTROL - unchanged)
#define GATHER4H(HWS)                                                           \
    float4 acc;                                                                 \
    {                                                                           \
        float4 s0 = load_h4(HWS, i, sub);                                       \
        acc = make_float4(2.f * s0.x, 2.f * s0.y, 2.f * s0.z, 2.f * s0.w);      \
        float4 a1 = make_float4(0.f, 0.f, 0.f, 0.f);                            \
        float4 a2 = a1, a3 = a1;                                                \
        int beg = offs[i], end = beg + degi[i];                                 \
        int j = beg;                                                            \
        for (; j + 3 < end; j += 4) {                                           \
            int r0 = srcs[j], r1 = srcs[j + 1], r2 = srcs[j + 2], r3 = srcs[j + 3]; \
            float4 q0 = load_h4(HWS, r0, sub);                                  \
            float4 q1 = load_h4(HWS, r1, sub);                                  \
            float4 q2 = load_h4(HWS, r2, sub);                                  \
            float4 q3 = load_h4(HWS, r3, sub);                                  \
            acc.x += q0.x; acc.y += q0.y; acc.z += q0.z; acc.w += q0.w;         \
            a1.x += q1.x; a1.y += q1.y; a1.z += q1.z; a1.w += q1.w;             \
            a2.x += q2.x; a2.y += q2.y; a2.z += q2.z; a2.w += q2.w;             \
            a3.x += q3.x; a3.y += q3.y; a3.z += q3.z; a3.w += q3.w;             \
        }                                                                       \
        for (; j < end; j++) {                                                  \
            float4 q0 = load_h4(HWS, srcs[j], sub);                             \
            acc.x += q0.x; acc.y += q0.y; acc.z += q0.z; acc.w += q0.w;         \
        }                                                                       \
        acc.x += a1.x + a2.x + a3.x;                                            \
        acc.y += a1.y + a2.y + a3.y;                                            \
        acc.z += a1.z + a2.z + a3.z;                                            \
        acc.w += a1.w + a2.w + a3.w;                                            \
    }

// layer-2 aggregate + relu (-> h2), pool accumulation, layer-3 transform
__global__ void __launch_bounds__(BLK) k_agg2(const __half* __restrict__ hwsB,
                                              const int* __restrict__ offs,
                                              const int* __restrict__ degi,
                                              const int* __restrict__ srcs,
                                              const float* __restrict__ dinv,
                                              const float* __restrict__ b2,
                                              const float* __restrict__ W3,
                                              float* __restrict__ hws3,
                                              float* __restrict__ pool, int n) {
    __shared__ float w3[16];
    __shared__ float bb[16];
    __shared__ float lp[16];
    int tid = threadIdx.x;
    if (tid < 16) { w3[tid] = W3[tid]; bb[tid] = b2[tid]; lp[tid] = 0.f; }
    __syncthreads();
    int nl = tid >> 2, sub = tid & 3;
    int i = blockIdx.x * 64 + nl;
    bool act = (i < n);
    float4 h = make_float4(0.f, 0.f, 0.f, 0.f);
    if (act) {
        float di = dinv[i];
        GATHER4H(hwsB);
        h.x = fmaxf(di * acc.x + bb[sub * 4 + 0], 0.f);
        h.y = fmaxf(di * acc.y + bb[sub * 4 + 1], 0.f);
        h.z = fmaxf(di * acc.z + bb[sub * 4 + 2], 0.f);
        h.w = fmaxf(di * acc.w + bb[sub * 4 + 3], 0.f);
        float p = h.x * w3[sub * 4 + 0] + h.y * w3[sub * 4 + 1]
                + h.z * w3[sub * 4 + 2] + h.w * w3[sub * 4 + 3];
        p += __shfl_xor(p, 1);
        p += __shfl_xor(p, 2);
        if (sub == 0) hws3[i] = di * p;
    }
    float4 hp = h;
#pragma unroll
    for (int m = 4; m < 64; m <<= 1) {
        hp.x += __shfl_xor(hp.x, m);
        hp.y += __shfl_xor(hp.y, m);
        hp.z += __shfl_xor(hp.z, m);
        hp.w += __shfl_xor(hp.w, m);
    }
    if ((tid & 63) < 4) {
        atomicAdd(&lp[sub * 4 + 0], hp.x);
        atomicAdd(&lp[sub * 4 + 1], hp.y);
        atomicAdd(&lp[sub * 4 + 2], hp.z);
        atomicAdd(&lp[sub * 4 + 3], hp.w);
    }
    __syncthreads();
    if (tid < 16) atomicAdd(&pool[tid], lp[tid]);
}

// layer-3 aggregate -> logits c[n]; per-block max of masked logits
__global__ void __launch_bounds__(BLK) k_agg3(const float* __restrict__ hws3,
                                              const int* __restrict__ offs,
                                              const int* __restrict__ degi,
                                              const int* __restrict__ srcs,
                                              const float* __restrict__ dinv,
                                              const float* __restrict__ b3,
                                              const int* __restrict__ choices,
                                              float* __restrict__ cbuf,
                                              float* __restrict__ pmax, int n) {
    __shared__ float red[BLK];
    int tid = threadIdx.x;
    int nl = tid >> 2, sub = tid & 3;
    int i = blockIdx.x * 64 + nl;
    bool act = (i < n);
    float s = 0.f;
    if (act) {
        int beg = offs[i], end = beg + degi[i];
        for (int j = beg + sub; j < end; j += 4) s += hws3[srcs[j]];
    }
    s += __shfl_xor(s, 1);
    s += __shfl_xor(s, 2);
    float logit = -INFINITY;
    if (act && sub == 0) {
        float c = dinv[i] * (s + 2.f * hws3[i]) + b3[0];
        cbuf[i] = c;
        if (choices[i] != 0) logit = c;
    }
    red[tid] = logit;
    __syncthreads();
    for (int d = BLK / 2; d > 0; d >>= 1) {
        if (tid < d) red[tid] = fmaxf(red[tid], red[tid + d]);
        __syncthreads();
    }
    if (tid == 0) pmax[blockIdx.x] = red[0];
}

__global__ void k_redmax(const float* __restrict__ pmax, float* __restrict__ scal_m, int nblk) {
    __shared__ float red[BLK];
    float m = -INFINITY;
    for (int i = threadIdx.x; i < nblk; i += BLK) m = fmaxf(m, pmax[i]);
    red[threadIdx.x] = m;
    __syncthreads();
    for (int d = BLK / 2; d > 0; d >>= 1) {
        if (threadIdx.x < d) red[threadIdx.x] = fmaxf(red[threadIdx.x], red[threadIdx.x + d]);
        __syncthreads();
    }
    if (threadIdx.x == 0) scal_m[0] = red[0];
}

__global__ void __launch_bounds__(BLK) k_sumexp(const float* __restrict__ cbuf,
                                                const int* __restrict__ choices,
                                                const float* __restrict__ scal_m,
                                                float* __restrict__ Ssum, int n) {
    __shared__ float red[BLK];
    int i = blockIdx.x * BLK + threadIdx.x;
    float m = scal_m[0];
    float v = 0.0f;
    if (i < n && choices[i] != 0) v = expf(cbuf[i] - m);
    red[threadIdx.x] = v;
    __syncthreads();
    for (int d = BLK / 2; d > 0; d >>= 1) {
        if (threadIdx.x < d) red[threadIdx.x] += red[threadIdx.x + d];
        __syncthreads();
    }
    if (threadIdx.x == 0) atomicAdd(Ssum, red[0]);
}

__global__ void __launch_bounds__(BLK) k_final(const float* __restrict__ cbuf,
                                               const int* __restrict__ choices,
                                               const float* __restrict__ scal_m,
                                               const float* __restrict__ Ssum,
                                               const float* __restrict__ pool,
                                               const float* __restrict__ fcw,
                                               const float* __restrict__ fcb,
                                               float* __restrict__ out, int n) {
    int i = blockIdx.x * BLK + threadIdx.x;
    if (i < n) {
        float p = 0.0f;
        if (choices[i] != 0) {
            float m = scal_m[0], S = Ssum[0];
            p = expf(cbuf[i] - m) / S;
        }
        out[i] = p;
    }
    if (blockIdx.x == 0 && threadIdx.x == 0) {
        float invn = 1.0f / (float)n;
        float v = 0.0f;
#pragma unroll
        for (int f = 0; f < 16; f++) v += (pool[f] * invn) * fcw[f];
        out[n] = v + fcb[0];
    }
}

extern "C" void kernel_launch(void* const* d_in, const int* in_sizes, int n_in,
                              void* d_out, int out_size, void* d_ws, size_t ws_size,
                              hipStream_t stream) {
    const float* x       = (const float*)d_in[0];
    const int*   ei      = (const int*)d_in[1];
    const int*   choices = (const int*)d_in[2];
    const float* W1 = (const float*)d_in[3];
    const float* b1 = (const float*)d_in[4];
    const float* W2 = (const float*)d_in[5];
    const float* b2 = (const float*)d_in[6];
    const float* W3 = (const float*)d_in[7];
    const float* b3 = (const float*)d_in[8];
    const float* fcw = (const float*)d_in[9];
    const float* fcb = (const float*)d_in[10];
    float* out = (float*)d_out;

    int n = in_sizes[0] / 3;
    int E = in_sizes[1] / 2;
    const int* row = ei;
    const int* col = ei + E;

    int nblkN = (n + BLK - 1) / BLK;           // 391
    int nblk64 = (n + 63) / 64;                // 1563  (4 lanes/node kernels)
    int nbuck = (n + (1 << BSH) - 1) >> BSH;   // 391 buckets of 256 nodes
    int nblkBin = (E + EB - 1) / EB;           // 391 binning blocks

    // workspace layout (16B aligned slices)
    char* ws = (char*)d_ws;
    size_t o = 0;
    auto alloc = [&](size_t bytes) { char* p = ws + o; o += (bytes + 15) & ~(size_t)15; return p; };
    int*   degi   = (int*)  alloc((size_t)n * 4);
    int*   offs   = (int*)  alloc((size_t)n * 4);
    float* dinv   = (float*)alloc((size_t)n * 4);
    float* hws3   = (float*)alloc((size_t)n * 4);
    float* cbuf   = (float*)alloc((size_t)n * 4);
    float* pmax   = (float*)alloc(16384);      // >= nblk64 floats
    int*   bcnt   = (int*)  alloc(NB * 4);
    int*   gcur   = (int*)  alloc(NB * 4);
    int*   bbase  = (int*)  alloc(NB * 4);
    float* scal   = (float*)alloc(256);   // [0]=S, [1..16]=pool, [17]=m
    float* Ssum   = scal + 0;
    float* pool   = scal + 1;
    float* scal_m = scal + 17;
    __half* xs    = (__half*)alloc((size_t)n * 4 * 2);   // half4 per node
    size_t hw_bytes = (size_t)n * 16 * 2;                // hwsB (fp16)
    size_t pk_bytes = (size_t)E * 4;                     // packed (aliases hwsB)
    char*  blob   = alloc(hw_bytes > pk_bytes ? hw_bytes : pk_bytes);
    int*    packed = (int*)blob;          // build phase only; dead before k_agg1
    __half* hwsB   = (__half*)blob;
    int*   srcs   = (int*)  alloc((size_t)E * 4);
    (void)ws_size;

    hipMemsetAsync(bcnt, 0, NB * 4, stream);
    hipMemsetAsync(scal, 0, 68, stream);   // S + pool[16]

    // ---- CSR build ----
    k_bcount<<<nblkBin, BLK, 0, stream>>>(col, bcnt, E);
    k_bscan<<<1, NB, 0, stream>>>(bcnt, gcur, bbase, nbuck);
    k_bin<<<nblkBin, BINTH, 0, stream>>>(row, col, gcur, packed, E);
    k_place<<<nbuck, BLK, 0, stream>>>(packed, bbase, bcnt, x, degi, offs, dinv, xs, srcs, n);

    // ---- GCN layers ----
    k_agg1<<<nblk64, BLK, 0, stream>>>(xs, offs, degi, srcs, dinv, b1, W1, W2, hwsB, n);
    k_agg2<<<nblk64, BLK, 0, stream>>>(hwsB, offs, degi, srcs, dinv, b2, W3, hws3, pool, n);
    k_agg3<<<nblk64, BLK, 0, stream>>>(hws3, offs, degi, srcs, dinv, b3, choices, cbuf, pmax, n);

    // ---- softmax + value head ----
    k_redmax<<<1, BLK, 0, stream>>>(pmax, scal_m, nblk64);
    k_sumexp<<<nblkN, BLK, 0, stream>>>(cbuf, choices, scal_m, Ssum, n);
    k_final<<<nblkN, BLK, 0, stream>>>(cbuf, choices, scal_m, Ssum, pool, fcw, fcb, out, n);
}

// Round 9
// 249.171 us; speedup vs baseline: 3.5637x; 1.0474x over previous
//
#include <hip/hip_runtime.h>
#include <hip/hip_fp16.h>
#include <math.h>

#define BLK 256

// ---------------------------------------------------------------------------
// GCNPolicyNetwork: 3-layer improved-GCN + masked softmax + mean-pool value.
// Round 9: build-phase slimming + gather MSHR test.
//  - Fixed-capacity buckets (CAP=10240 per 256-node bucket): k_bin reserves
//    space directly -> k_bcount/k_bscan DELETED. k_place computes the tight
//    CSR base with an in-block reduction over bucket counts (srcs stays tight).
//  - k_redmax DELETED: k_agg3 block-reduces then one encoded-uint atomicMax
//    per block (monotone float<->uint map).
//  - 2 memsets -> k_init. Dispatches 13 -> 8.
//  - k_agg2/k_agg3 gather unroll 4->8 (srcs batch prefetch): falsifiable test
//    of the per-CU outstanding-miss (MSHR x L2-latency) ceiling theory; if
//    k_agg2 stays ~49us the ceiling is confirmed.
// Gather structure itself is R5/R8's node-centric 4-lane fp16 (best known;
// R6 lane remap and R7 edge-centric LDS atomics both regressed).
// ---------------------------------------------------------------------------

#define BSH 8                    // 256 nodes per bucket
#define NB 512                   // bucket-array size (nbuck=391 <= 512)
#define CAP 10240                // packed[] capacity per bucket (mean ~8184)
#define EB 8192                  // edges per binning block
#define BINTH 512                // k_bin block size

// ---- fp16 payload helpers ----
__device__ inline float4 load_h4(const __half* base, int node, int sub) {
    const uint2* p = reinterpret_cast<const uint2*>(base + ((size_t)node << 4)) + sub;
    uint2 u = *p;
    union { unsigned u; __half2 h; } a, b;
    a.u = u.x; b.u = u.y;
    float2 fa = __half22float2(a.h), fb = __half22float2(b.h);
    return make_float4(fa.x, fa.y, fb.x, fb.y);
}

__device__ inline void store_h4(__half* base, int node, int sub, float4 v) {
    union { unsigned u; __half2 h; } a, b;
    a.h = __floats2half2_rn(v.x, v.y);
    b.h = __floats2half2_rn(v.z, v.w);
    uint2 u; u.x = a.u; u.y = b.u;
    *(reinterpret_cast<uint2*>(base + ((size_t)node << 4)) + sub) = u;
}

// xs payload: half4 (dinv*x0, dinv*x1, dinv*x2, 0) = 8 B per node
__device__ inline float3 load_xs(const __half* xs, int node) {
    uint2 u = *reinterpret_cast<const uint2*>(xs + ((size_t)node << 2));
    union { unsigned u; __half2 h; } a, b;
    a.u = u.x; b.u = u.y;
    float2 fa = __half22float2(a.h), fb = __half22float2(b.h);
    return make_float3(fa.x, fa.y, fb.x);
}

// monotone float<->uint encoding for atomicMax over signed floats
__device__ inline unsigned encf(float f) {
    unsigned u = __float_as_uint(f);
    return (u & 0x80000000u) ? ~u : (u | 0x80000000u);
}
__device__ inline float decf(unsigned e) {
    return (e & 0x80000000u) ? __uint_as_float(e ^ 0x80000000u)
                             : __uint_as_float(~e);
}

// zero gcur[NB] + scal[18] (Ssum, pool[16], maxenc)
__global__ void k_init(int* __restrict__ gcur, float* __restrict__ scal) {
    int t = threadIdx.x;
    gcur[t] = 0;
    if (t < 18) scal[t] = 0.f;
}

// LDS multisplit of edges into 256-node buckets; reserve directly in the
// fixed-capacity packed[] layout (bucket b owns [b*CAP, b*CAP+cnt)).
__global__ void __launch_bounds__(BINTH) k_bin(const int* __restrict__ row,
                                               const int* __restrict__ col,
                                               int* __restrict__ gcur,
                                               int* __restrict__ packed, int E) {
    __shared__ int stage[EB];
    __shared__ unsigned short sbuk[EB];
    __shared__ int hist[NB];
    __shared__ int lscan[NB];
    __shared__ int cur[NB];
    __shared__ int gbase[NB];
    int tid = threadIdx.x;
    int base = blockIdx.x * EB;
    int cnt = min(EB, E - base);

    hist[tid] = 0;
    __syncthreads();
    for (int j = tid; j < cnt; j += BINTH) {
        int c = __builtin_nontemporal_load(col + base + j);
        atomicAdd(&hist[c >> BSH], 1);
    }
    __syncthreads();
    lscan[tid] = hist[tid];
    __syncthreads();
    for (int d = 1; d < NB; d <<= 1) {
        int t = (tid >= d) ? lscan[tid - d] : 0;
        __syncthreads();
        if (tid >= d) lscan[tid] += t;
        __syncthreads();
    }
    {
        int ex = lscan[tid] - hist[tid];
        lscan[tid] = ex;
        cur[tid] = ex;
    }
    __syncthreads();
    for (int j = tid; j < cnt; j += BINTH) {
        int c = __builtin_nontemporal_load(col + base + j);
        int r = __builtin_nontemporal_load(row + base + j);
        int b = c >> BSH;
        int p = atomicAdd(&cur[b], 1);
        stage[p] = (r << BSH) | (c & ((1 << BSH) - 1));
        sbuk[p] = (unsigned short)b;
    }
    __syncthreads();
    if (hist[tid] > 0) gbase[tid] = tid * CAP + atomicAdd(&gcur[tid], hist[tid]);
    __syncthreads();
    for (int j = tid; j < cnt; j += BINTH) {
        int b = sbuk[j];
        int pos = gbase[b] + (j - lscan[b]);
        packed[pos] = stage[j];
    }
}

// per-bucket: tight CSR base (reduce over bucket counts) + degree hist/scan
// -> degi/offs/dinv/xs, then fine placement into srcs (tight layout).
__global__ void __launch_bounds__(BLK) k_place(const int* __restrict__ packed,
                                               const int* __restrict__ bcnt,
                                               const float* __restrict__ x,
                                               int* __restrict__ degi,
                                               int* __restrict__ offs,
                                               float* __restrict__ dinv,
                                               __half* __restrict__ xs,
                                               int* __restrict__ srcs, int n) {
    __shared__ int cnt[256];
    __shared__ int lcur[256];
    __shared__ int ssum[256];
    __shared__ int psum[256];
    int tid = threadIdx.x;
    int b = blockIdx.x;
    // tight base: sum of bcnt[b'] for b' < b
    int pv = 0;
    for (int t = tid; t < b; t += BLK) pv += bcnt[t];
    psum[tid] = pv;
    cnt[tid] = 0;
    __syncthreads();
    for (int d = BLK / 2; d > 0; d >>= 1) {
        if (tid < d) psum[tid] += psum[tid + d];
        __syncthreads();
    }
    int pbeg = psum[0];
    int ecnt = bcnt[b];
    const int* pk = packed + (size_t)b * CAP;
    for (int j = tid; j < ecnt; j += BLK)
        atomicAdd(&cnt[pk[j] & 255], 1);
    __syncthreads();
    int c = cnt[tid];
    ssum[tid] = c;
    __syncthreads();
    for (int d = 1; d < 256; d <<= 1) {
        int t = (tid >= d) ? ssum[tid - d] : 0;
        __syncthreads();
        if (tid >= d) ssum[tid] += t;
        __syncthreads();
    }
    int ex = ssum[tid] - c;
    lcur[tid] = ex;
    int i = (b << BSH) + tid;
    if (i < n) {
        degi[i] = c;
        offs[i] = pbeg + ex;
        float di = rsqrtf((float)c + 2.0f);
        dinv[i] = di;
        float x0 = x[i * 3 + 0], x1 = x[i * 3 + 1], x2 = x[i * 3 + 2];
        union { unsigned u; __half2 h; } a2, b2;
        a2.h = __floats2half2_rn(di * x0, di * x1);
        b2.h = __floats2half2_rn(di * x2, 0.f);
        uint2 u; u.x = a2.u; u.y = b2.u;
        *reinterpret_cast<uint2*>(xs + ((size_t)i << 2)) = u;
    }
    __syncthreads();
    for (int j = tid; j < ecnt; j += BLK) {
        int v = pk[j];
        int li = v & 255;
        int slot = atomicAdd(&lcur[li], 1);
        srcs[pbeg + slot] = v >> BSH;
    }
}

// layer-1: rank-3 aggregation of xs, then @W1 + relu, then @W2 -> hwsB (fp16).
__global__ void __launch_bounds__(BLK) k_agg1(const __half* __restrict__ xs,
                                              const int* __restrict__ offs,
                                              const int* __restrict__ degi,
                                              const int* __restrict__ srcs,
                                              const float* __restrict__ dinv,
                                              const float* __restrict__ b1,
                                              const float* __restrict__ W1,
                                              const float* __restrict__ W2,
                                              __half* __restrict__ hwsB, int n) {
    __shared__ float w1[48];
    __shared__ float w2[256];
    __shared__ float bb[16];
    __shared__ float hbuf[64][17];
    int tid = threadIdx.x;
    w2[tid] = W2[tid];
    if (tid < 48) w1[tid] = W1[tid];
    if (tid < 16) bb[tid] = b1[tid];
    __syncthreads();
    int nl = tid >> 2, sub = tid & 3;
    int i = blockIdx.x * 64 + nl;
    bool act = (i < n);
    float di = 0.f;
    if (act) {
        di = dinv[i];
        float ax = 0.f, ay = 0.f, az = 0.f;
        float bx = 0.f, by = 0.f, bz = 0.f;
        int beg = offs[i], end = beg + degi[i];
        int j = beg + sub;
        for (; j + 12 < end; j += 16) {
            int r0 = srcs[j], r1 = srcs[j + 4], r2 = srcs[j + 8], r3 = srcs[j + 12];
            float3 q0 = load_xs(xs, r0);
            float3 q1 = load_xs(xs, r1);
            float3 q2 = load_xs(xs, r2);
            float3 q3 = load_xs(xs, r3);
            ax += q0.x; ay += q0.y; az += q0.z;
            bx += q1.x; by += q1.y; bz += q1.z;
            ax += q2.x; ay += q2.y; az += q2.z;
            bx += q3.x; by += q3.y; bz += q3.z;
        }
        for (; j < end; j += 4) {
            float3 q0 = load_xs(xs, srcs[j]);
            ax += q0.x; ay += q0.y; az += q0.z;
        }
        ax += bx; ay += by; az += bz;
        ax += __shfl_xor(ax, 1); ay += __shfl_xor(ay, 1); az += __shfl_xor(az, 1);
        ax += __shfl_xor(ax, 2); ay += __shfl_xor(ay, 2); az += __shfl_xor(az, 2);
        float3 s = load_xs(xs, i);
        ax += 2.f * s.x; ay += 2.f * s.y; az += 2.f * s.z;
#pragma unroll
        for (int k = 0; k < 4; k++) {
            int f = sub * 4 + k;
            float hv = di * (ax * w1[f] + ay * w1[16 + f] + az * w1[32 + f]) + bb[f];
            hbuf[nl][f] = fmaxf(hv, 0.f);
        }
    }
    __syncthreads();
    if (act) {
        const float* hn = hbuf[nl];
        float s0 = 0.f, s1 = 0.f, s2 = 0.f, s3 = 0.f;
#pragma unroll
        for (int f = 0; f < 16; f++) {
            float hv = hn[f];
            const float4 wq = *(const float4*)&w2[f * 16 + sub * 4];
            s0 += hv * wq.x; s1 += hv * wq.y; s2 += hv * wq.z; s3 += hv * wq.w;
        }
        store_h4(hwsB, i, sub, make_float4(di * s0, di * s1, di * s2, di * s3));
    }
}

// node-centric 4-lane gather, fp16 payload, unroll x8 (srcs batch prefetch)
#define GATHER8H(HWS)                                                           \
    float4 acc;                                                                 \
    {                                                                           \
        float4 s0 = load_h4(HWS, i, sub);                                       \
        acc = make_float4(2.f * s0.x, 2.f * s0.y, 2.f * s0.z, 2.f * s0.w);      \
        float4 a1 = make_float4(0.f, 0.f, 0.f, 0.f);                            \
        float4 a2 = a1, a3 = a1;                                                \
        int beg = offs[i], end = beg + degi[i];                                 \
        int j = beg;                                                            \
        for (; j + 7 < end; j += 8) {                                           \
            int r0 = srcs[j],     r1 = srcs[j + 1], r2 = srcs[j + 2], r3 = srcs[j + 3]; \
            int r4 = srcs[j + 4], r5 = srcs[j + 5], r6 = srcs[j + 6], r7 = srcs[j + 7]; \
            float4 q0 = load_h4(HWS, r0, sub);                                  \
            float4 q1 = load_h4(HWS, r1, sub);                                  \
            float4 q2 = load_h4(HWS, r2, sub);                                  \
            float4 q3 = load_h4(HWS, r3, sub);                                  \
            float4 q4 = load_h4(HWS, r4, sub);                                  \
            float4 q5 = load_h4(HWS, r5, sub);                                  \
            float4 q6 = load_h4(HWS, r6, sub);                                  \
            float4 q7 = load_h4(HWS, r7, sub);                                  \
            acc.x += q0.x + q4.x; acc.y += q0.y + q4.y;                         \
            acc.z += q0.z + q4.z; acc.w += q0.w + q4.w;                         \
            a1.x += q1.x + q5.x; a1.y += q1.y + q5.y;                           \
            a1.z += q1.z + q5.z; a1.w += q1.w + q5.w;                           \
            a2.x += q2.x + q6.x; a2.y += q2.y + q6.y;                           \
            a2.z += q2.z + q6.z; a2.w += q2.w + q6.w;                           \
            a3.x += q3.x + q7.x; a3.y += q3.y + q7.y;                           \
            a3.z += q3.z + q7.z; a3.w += q3.w + q7.w;                           \
        }                                                                       \
        for (; j < end; j++) {                                                  \
            float4 q0 = load_h4(HWS, srcs[j], sub);                             \
            acc.x += q0.x; acc.y += q0.y; acc.z += q0.z; acc.w += q0.w;         \
        }                                                                       \
        acc.x += a1.x + a2.x + a3.x;                                            \
        acc.y += a1.y + a2.y + a3.y;                                            \
        acc.z += a1.z + a2.z + a3.z;                                            \
        acc.w += a1.w + a2.w + a3.w;                                            \
    }

// layer-2 aggregate + relu (-> h2), pool accumulation, layer-3 transform
__global__ void __launch_bounds__(BLK) k_agg2(const __half* __restrict__ hwsB,
                                              const int* __restrict__ offs,
                                              const int* __restrict__ degi,
                                              const int* __restrict__ srcs,
                                              const float* __restrict__ dinv,
                                              const float* __restrict__ b2,
                                              const float* __restrict__ W3,
                                              float* __restrict__ hws3,
                                              float* __restrict__ pool, int n) {
    __shared__ float w3[16];
    __shared__ float bb[16];
    __shared__ float lp[16];
    int tid = threadIdx.x;
    if (tid < 16) { w3[tid] = W3[tid]; bb[tid] = b2[tid]; lp[tid] = 0.f; }
    __syncthreads();
    int nl = tid >> 2, sub = tid & 3;
    int i = blockIdx.x * 64 + nl;
    bool act = (i < n);
    float4 h = make_float4(0.f, 0.f, 0.f, 0.f);
    if (act) {
        float di = dinv[i];
        GATHER8H(hwsB);
        h.x = fmaxf(di * acc.x + bb[sub * 4 + 0], 0.f);
        h.y = fmaxf(di * acc.y + bb[sub * 4 + 1], 0.f);
        h.z = fmaxf(di * acc.z + bb[sub * 4 + 2], 0.f);
        h.w = fmaxf(di * acc.w + bb[sub * 4 + 3], 0.f);
        float p = h.x * w3[sub * 4 + 0] + h.y * w3[sub * 4 + 1]
                + h.z * w3[sub * 4 + 2] + h.w * w3[sub * 4 + 3];
        p += __shfl_xor(p, 1);
        p += __shfl_xor(p, 2);
        if (sub == 0) hws3[i] = di * p;
    }
    float4 hp = h;
#pragma unroll
    for (int m = 4; m < 64; m <<= 1) {
        hp.x += __shfl_xor(hp.x, m);
        hp.y += __shfl_xor(hp.y, m);
        hp.z += __shfl_xor(hp.z, m);
        hp.w += __shfl_xor(hp.w, m);
    }
    if ((tid & 63) < 4) {
        atomicAdd(&lp[sub * 4 + 0], hp.x);
        atomicAdd(&lp[sub * 4 + 1], hp.y);
        atomicAdd(&lp[sub * 4 + 2], hp.z);
        atomicAdd(&lp[sub * 4 + 3], hp.w);
    }
    __syncthreads();
    if (tid < 16) atomicAdd(&pool[tid], lp[tid]);
}

// layer-3 aggregate -> logits c[n]; block max -> one encoded atomicMax
__global__ void __launch_bounds__(BLK) k_agg3(const float* __restrict__ hws3,
                                              const int* __restrict__ offs,
                                              const int* __restrict__ degi,
                                              const int* __restrict__ srcs,
                                              const float* __restrict__ dinv,
                                              const float* __restrict__ b3,
                                              const int* __restrict__ choices,
                                              float* __restrict__ cbuf,
                                              unsigned* __restrict__ menc, int n) {
    __shared__ float red[BLK];
    int tid = threadIdx.x;
    int nl = tid >> 2, sub = tid & 3;
    int i = blockIdx.x * 64 + nl;
    bool act = (i < n);
    float s = 0.f;
    if (act) {
        int beg = offs[i], end = beg + degi[i];
        int j = beg + sub;
        float s1 = 0.f;
        for (; j + 4 < end; j += 8) {
            float q0 = hws3[srcs[j]];
            float q1 = hws3[srcs[j + 4]];
            s += q0; s1 += q1;
        }
        if (j < end) s += hws3[srcs[j]];
        s += s1;
    }
    s += __shfl_xor(s, 1);
    s += __shfl_xor(s, 2);
    float logit = -INFINITY;
    if (act && sub == 0) {
        float c = dinv[i] * (s + 2.f * hws3[i]) + b3[0];
        cbuf[i] = c;
        if (choices[i] != 0) logit = c;
    }
    red[tid] = logit;
    __syncthreads();
    for (int d = BLK / 2; d > 0; d >>= 1) {
        if (tid < d) red[tid] = fmaxf(red[tid], red[tid + d]);
        __syncthreads();
    }
    if (tid == 0) atomicMax(menc, encf(red[0]));
}

__global__ void __launch_bounds__(BLK) k_sumexp(const float* __restrict__ cbuf,
                                                const int* __restrict__ choices,
                                                const unsigned* __restrict__ menc,
                                                float* __restrict__ Ssum, int n) {
    __shared__ float red[BLK];
    int i = blockIdx.x * BLK + threadIdx.x;
    float m = decf(*menc);
    float v = 0.0f;
    if (i < n && choices[i] != 0) v = expf(cbuf[i] - m);
    red[threadIdx.x] = v;
    __syncthreads();
    for (int d = BLK / 2; d > 0; d >>= 1) {
        if (threadIdx.x < d) red[threadIdx.x] += red[threadIdx.x + d];
        __syncthreads();
    }
    if (threadIdx.x == 0) atomicAdd(Ssum, red[0]);
}

__global__ void __launch_bounds__(BLK) k_final(const float* __restrict__ cbuf,
                                               const int* __restrict__ choices,
                                               const unsigned* __restrict__ menc,
                                               const float* __restrict__ Ssum,
                                               const float* __restrict__ pool,
                                               const float* __restrict__ fcw,
                                               const float* __restrict__ fcb,
                                               float* __restrict__ out, int n) {
    int i = blockIdx.x * BLK + threadIdx.x;
    if (i < n) {
        float p = 0.0f;
        if (choices[i] != 0) {
            float m = decf(*menc), S = Ssum[0];
            p = expf(cbuf[i] - m) / S;
        }
        out[i] = p;
    }
    if (blockIdx.x == 0 && threadIdx.x == 0) {
        float invn = 1.0f / (float)n;
        float v = 0.0f;
#pragma unroll
        for (int f = 0; f < 16; f++) v += (pool[f] * invn) * fcw[f];
        out[n] = v + fcb[0];
    }
}

extern "C" void kernel_launch(void* const* d_in, const int* in_sizes, int n_in,
                              void* d_out, int out_size, void* d_ws, size_t ws_size,
                              hipStream_t stream) {
    const float* x       = (const float*)d_in[0];
    const int*   ei      = (const int*)d_in[1];
    const int*   choices = (const int*)d_in[2];
    const float* W1 = (const float*)d_in[3];
    const float* b1 = (const float*)d_in[4];
    const float* W2 = (const float*)d_in[5];
    const float* b2 = (const float*)d_in[6];
    const float* W3 = (const float*)d_in[7];
    const float* b3 = (const float*)d_in[8];
    const float* fcw = (const float*)d_in[9];
    const float* fcb = (const float*)d_in[10];
    float* out = (float*)d_out;

    int n = in_sizes[0] / 3;
    int E = in_sizes[1] / 2;
    const int* row = ei;
    const int* col = ei + E;

    int nblkN = (n + BLK - 1) / BLK;           // 391
    int nblk64 = (n + 63) / 64;                // 1563
    int nbuck = (n + (1 << BSH) - 1) >> BSH;   // 391 buckets of 256 nodes
    int nblkBin = (E + EB - 1) / EB;           // 391 binning blocks

    // workspace layout (16B aligned slices)
    char* ws = (char*)d_ws;
    size_t o = 0;
    auto alloc = [&](size_t bytes) { char* p = ws + o; o += (bytes + 15) & ~(size_t)15; return p; };
    int*   degi   = (int*)  alloc((size_t)n * 4);
    int*   offs   = (int*)  alloc((size_t)n * 4);
    float* dinv   = (float*)alloc((size_t)n * 4);
    float* hws3   = (float*)alloc((size_t)n * 4);
    float* cbuf   = (float*)alloc((size_t)n * 4);
    int*   gcur   = (int*)  alloc(NB * 4);
    float* scal   = (float*)alloc(256);   // [0]=S, [1..16]=pool, [17]=maxenc
    float* Ssum   = scal + 0;
    float* pool   = scal + 1;
    unsigned* menc = (unsigned*)(scal + 17);
    __half* xs    = (__half*)alloc((size_t)n * 4 * 2);   // half4 per node
    size_t hw_bytes = (size_t)n * 16 * 2;                // hwsB (fp16)
    size_t pk_bytes = (size_t)NB * CAP * 4;              // packed (capacity layout)
    char*  blob   = alloc(hw_bytes > pk_bytes ? hw_bytes : pk_bytes);
    int*    packed = (int*)blob;          // build phase only; dead before k_agg1
    __half* hwsB   = (__half*)blob;
    int*   srcs   = (int*)  alloc((size_t)E * 4);        // tight CSR
    (void)ws_size;  // ~37 MB used

    // ---- build (2 passes over edges; no per-edge global atomics) ----
    k_init<<<1, NB, 0, stream>>>(gcur, scal);
    k_bin<<<nblkBin, BINTH, 0, stream>>>(row, col, gcur, packed, E);
    k_place<<<nbuck, BLK, 0, stream>>>(packed, gcur, x, degi, offs, dinv, xs, srcs, n);

    // ---- GCN layers ----
    k_agg1<<<nblk64, BLK, 0, stream>>>(xs, offs, degi, srcs, dinv, b1, W1, W2, hwsB, n);
    k_agg2<<<nblk64, BLK, 0, stream>>>(hwsB, offs, degi, srcs, dinv, b2, W3, hws3, pool, n);
    k_agg3<<<nblk64, BLK, 0, stream>>>(hws3, offs, degi, srcs, dinv, b3, choices, cbuf, menc, n);

    // ---- softmax + value head ----
    k_sumexp<<<nblkN, BLK, 0, stream>>>(cbuf, choices, menc, Ssum, n);
    k_final<<<nblkN, BLK, 0, stream>>>(cbuf, choices, menc, Ssum, pool, fcw, fcb, out, n);
}